// Round 1
// baseline (781.107 us; speedup 1.0000x reference)
//
#include <hip/hip_runtime.h>

#define H 64
#define W 64
#define C 256
#define O 256
#define NB 8
#define KK 9
#define HW 4096
#define KTOT 2304   // 9*256

// ---------------- K0: transpose conv_w (O,C,3,3) -> Wt[(k*C+c)*O + o]
__global__ void transpose_w_kernel(const float* __restrict__ cw, float* __restrict__ Wt) {
    int tid = blockIdx.x * blockDim.x + threadIdx.x;
    if (tid >= KTOT * O) return;
    int o  = tid & 255;
    int kk = tid >> 8;       // k*C + c
    int k  = kk >> 8;
    int c  = kk & 255;
    Wt[tid] = cw[(size_t)o * KTOT + c * 9 + k];
}

// ---------------- K1: offset conv (18 ch) + sampling-param precompute
// one block per (b, ho); 576 threads = 9 k-waves x 64 wo
#define CH 16
__global__ __launch_bounds__(576) void offset_conv_kernel(
    const float* __restrict__ x, const float* __restrict__ ow,
    const float* __restrict__ ob, float* __restrict__ params)
{
    int blk = blockIdx.x;
    int b  = blk >> 6;
    int ho = blk & 63;
    int t  = threadIdx.x;
    int k  = t >> 6;         // wave-uniform (waves are 64 contiguous threads)
    int wo = t & 63;
    int ku = __builtin_amdgcn_readfirstlane(k);   // make weight loads scalar

    __shared__ float xs[CH][3][66];

    float dy = 0.f, dx = 0.f;

    for (int c0 = 0; c0 < C; c0 += CH) {
        __syncthreads();
        for (int idx = t; idx < CH * 3 * 66; idx += 576) {
            int ci  = idx / 198;
            int rem = idx - ci * 198;
            int r   = rem / 66;
            int col = rem - r * 66;
            int row = ho - 1 + r;
            int xc  = col - 1;
            float v = 0.f;
            if (row >= 0 && row < H && xc >= 0 && xc < W)
                v = x[(((size_t)b * C + c0 + ci) * H + row) * W + xc];
            xs[ci][r][col] = v;
        }
        __syncthreads();
        const float* wyp = ow + (size_t)(2 * ku) * KTOT + (size_t)c0 * 9;
        const float* wxp = ow + (size_t)(2 * ku + 1) * KTOT + (size_t)c0 * 9;
        for (int ci = 0; ci < CH; ci++) {
            #pragma unroll
            for (int r = 0; r < 3; r++) {
                #pragma unroll
                for (int s = 0; s < 3; s++) {
                    float v = xs[ci][r][wo + s];
                    dy += v * wyp[ci * 9 + r * 3 + s];
                    dx += v * wxp[ci * 9 + r * 3 + s];
                }
            }
        }
    }
    dy += ob[2 * ku];
    dx += ob[2 * ku + 1];

    float py = (float)(ho - 1 + ku / 3) + dy;
    float px = (float)(wo - 1 + ku % 3) + dx;
    float y0f = floorf(py), x0f = floorf(px);
    float4 prm;
    prm.x = __int_as_float((int)y0f);
    prm.y = __int_as_float((int)x0f);
    prm.z = py - y0f;
    prm.w = px - x0f;
    ((float4*)params)[((size_t)(b * KK + k)) * HW + ho * 64 + wo] = prm;
}

// ---------------- K2: fused gather + implicit GEMM
// tile: 128 o x 128 pixels, K-chunks of 32; 256 threads, 8o x 8p per thread
#define TP 128
#define TKC 32
__global__ __launch_bounds__(256, 4) void deform_gemm_kernel(
    const float* __restrict__ x, const float* __restrict__ Wt,
    const float* __restrict__ params, const float* __restrict__ cb,
    float* __restrict__ out)
{
    int p0 = blockIdx.x * TP;          // 32 pixel tiles
    int o0 = blockIdx.y * 128;         // 2 o tiles
    int b  = blockIdx.z;
    int t  = threadIdx.x;

    __shared__ float S[TKC][TP];       // 16 KB
    __shared__ float Wl[TKC][128];     // 16 KB

    float acc[8][8];
    #pragma unroll
    for (int i = 0; i < 8; i++)
        #pragma unroll
        for (int j = 0; j < 8; j++) acc[i][j] = 0.f;

    const int pg  = t & 15;            // pixel group (8 pixels)
    const int og  = t >> 4;            // o group (8 outputs)
    const int sp  = t & 127;           // staging pixel
    const int skk = t >> 7;            // 0/1

    const float4* params4 = (const float4*)params;

    for (int ch = 0; ch < 72; ch++) {
        int k     = ch >> 3;
        int cbase = (ch & 7) * TKC;

        // per-thread sampling params for staging pixel (issued before barrier)
        float4 prm = params4[((size_t)(b * KK + k)) * HW + p0 + sp];
        int y0 = __float_as_int(prm.x);
        int x0 = __float_as_int(prm.y);
        float wyf = prm.z, wxf = prm.w;
        int y1 = y0 + 1, x1 = x0 + 1;
        bool vy0 = (y0 >= 0) & (y0 < H);
        bool vy1 = (y1 >= 0) & (y1 < H);
        bool vx0 = (x0 >= 0) & (x0 < W);
        bool vx1 = (x1 >= 0) & (x1 < W);
        float w00 = (vy0 & vx0) ? (1.f - wyf) * (1.f - wxf) : 0.f;
        float w01 = (vy0 & vx1) ? (1.f - wyf) * wxf : 0.f;
        float w10 = (vy1 & vx0) ? wyf * (1.f - wxf) : 0.f;
        float w11 = (vy1 & vx1) ? wyf * wxf : 0.f;
        int yc0 = min(max(y0, 0), H - 1), yc1 = min(max(y1, 0), H - 1);
        int xc0 = min(max(x0, 0), W - 1), xc1 = min(max(x1, 0), W - 1);
        int i00 = yc0 * W + xc0, i01 = yc0 * W + xc1;
        int i10 = yc1 * W + xc0, i11 = yc1 * W + xc1;

        __syncthreads();   // previous compute done before overwriting LDS

        // stage S[32][128]: this thread fills 16 channels at its pixel
        const float* xb = x + ((size_t)b * C + cbase + skk) * HW;
        #pragma unroll 4
        for (int i = 0; i < 16; i++) {
            const float* xp = xb + (size_t)(2 * i) * HW;
            float v = w00 * xp[i00] + w01 * xp[i01] + w10 * xp[i10] + w11 * xp[i11];
            S[skk + 2 * i][sp] = v;
        }
        // stage Wl[32][128] (coalesced)
        {
            const float* wbase = Wt + ((size_t)(k * C + cbase)) * O + o0;
            #pragma unroll
            for (int i = 0; i < 4; i++) {
                int f  = t + 256 * i;
                int kk = f >> 5;
                int oc = (f & 31) * 4;
                *(float4*)&Wl[kk][oc] = *(const float4*)&wbase[(size_t)kk * O + oc];
            }
        }
        __syncthreads();

        #pragma unroll 4
        for (int kk = 0; kk < TKC; kk++) {
            float sv[8], wv[8];
            *(float4*)&sv[0] = *(const float4*)&S[kk][pg * 8];
            *(float4*)&sv[4] = *(const float4*)&S[kk][pg * 8 + 4];
            *(float4*)&wv[0] = *(const float4*)&Wl[kk][og * 8];
            *(float4*)&wv[4] = *(const float4*)&Wl[kk][og * 8 + 4];
            #pragma unroll
            for (int oi = 0; oi < 8; oi++)
                #pragma unroll
                for (int pi = 0; pi < 8; pi++)
                    acc[oi][pi] += wv[oi] * sv[pi];
        }
    }

    // epilogue: add bias, write out
    #pragma unroll
    for (int oi = 0; oi < 8; oi++) {
        int o = o0 + og * 8 + oi;
        float bias = cb[o];
        float* op = out + ((size_t)b * O + o) * HW + p0 + pg * 8;
        float4 v0, v1;
        v0.x = acc[oi][0] + bias; v0.y = acc[oi][1] + bias;
        v0.z = acc[oi][2] + bias; v0.w = acc[oi][3] + bias;
        v1.x = acc[oi][4] + bias; v1.y = acc[oi][5] + bias;
        v1.z = acc[oi][6] + bias; v1.w = acc[oi][7] + bias;
        *(float4*)op       = v0;
        *(float4*)(op + 4) = v1;
    }
}

extern "C" void kernel_launch(void* const* d_in, const int* in_sizes, int n_in,
                              void* d_out, int out_size, void* d_ws, size_t ws_size,
                              hipStream_t stream) {
    const float* x  = (const float*)d_in[0];
    const float* ow = (const float*)d_in[1];
    const float* ob = (const float*)d_in[2];
    const float* cw = (const float*)d_in[3];
    const float* cb = (const float*)d_in[4];
    float* out = (float*)d_out;

    char* ws = (char*)d_ws;
    float* params = (float*)ws;                       // 8*9*4096*16B = 4,718,592 B
    float* Wt     = (float*)(ws + 4718592);           // 2304*256*4B  = 2,359,296 B

    transpose_w_kernel<<<(KTOT * O + 255) / 256, 256, 0, stream>>>(cw, Wt);
    offset_conv_kernel<<<NB * 64, 576, 0, stream>>>(x, ow, ob, params);
    deform_gemm_kernel<<<dim3(32, 2, NB), 256, 0, stream>>>(x, Wt, params, cb, out);
}

// Round 2
// 444.889 us; speedup vs baseline: 1.7557x; 1.7557x over previous
//
#include <hip/hip_runtime.h>

#define H 64
#define W 64
#define C 256
#define O 256
#define NB 8
#define KK 9
#define HW 4096
#define KTOT 2304   // 9*256

typedef _Float16 f16;
typedef _Float16 f16x8 __attribute__((ext_vector_type(8)));
typedef float f32x4 __attribute__((ext_vector_type(4)));

// ---------------- K0: conv_w (O,C,3,3) fp32 -> Wt2[o][k*256+c] f16
__global__ void wconv_kernel(const float* __restrict__ cw, f16* __restrict__ Wt2) {
    int tid = blockIdx.x * blockDim.x + threadIdx.x;  // o*2304 + k*256 + c
    if (tid >= O * KTOT) return;
    int o = tid / KTOT;
    int r = tid - o * KTOT;
    int k = r >> 8;
    int c = r & 255;
    Wt2[tid] = (f16)cw[o * KTOT + c * 9 + k];
}

// ---------------- transpose x (B,C,HW) -> x_t (B,HW,C)
__global__ __launch_bounds__(256) void transpose_x_kernel(
    const float* __restrict__ x, float* __restrict__ xt)
{
    __shared__ float tile[64][65];
    int b   = blockIdx.z;
    int yx0 = blockIdx.x * 64;
    int c0  = blockIdx.y * 64;
    int t = threadIdx.x;
    int j = t & 63, q = t >> 6;
    #pragma unroll 4
    for (int i = 0; i < 16; i++) {
        int c = c0 + q * 16 + i;
        tile[q * 16 + i][j] = x[((size_t)(b * C + c)) * HW + yx0 + j];
    }
    __syncthreads();
    #pragma unroll 4
    for (int i = 0; i < 16; i++) {
        int yx = yx0 + q * 16 + i;
        xt[((size_t)(b * HW + yx)) * C + c0 + j] = tile[j][q * 16 + i];
    }
}

// ---------------- K1: offset conv (18 ch) + sampling-param precompute
#define CH 16
__global__ __launch_bounds__(576) void offset_conv_kernel(
    const float* __restrict__ x, const float* __restrict__ ow,
    const float* __restrict__ ob, float* __restrict__ params)
{
    int blk = blockIdx.x;
    int b  = blk >> 6;
    int ho = blk & 63;
    int t  = threadIdx.x;
    int k  = t >> 6;
    int wo = t & 63;
    int ku = __builtin_amdgcn_readfirstlane(k);

    __shared__ float xs[CH][3][66];

    float dy = 0.f, dx = 0.f;

    for (int c0 = 0; c0 < C; c0 += CH) {
        __syncthreads();
        for (int idx = t; idx < CH * 3 * 66; idx += 576) {
            int ci  = idx / 198;
            int rem = idx - ci * 198;
            int r   = rem / 66;
            int col = rem - r * 66;
            int row = ho - 1 + r;
            int xc  = col - 1;
            float v = 0.f;
            if (row >= 0 && row < H && xc >= 0 && xc < W)
                v = x[(((size_t)b * C + c0 + ci) * H + row) * W + xc];
            xs[ci][r][col] = v;
        }
        __syncthreads();
        const float* wyp = ow + (size_t)(2 * ku) * KTOT + (size_t)c0 * 9;
        const float* wxp = ow + (size_t)(2 * ku + 1) * KTOT + (size_t)c0 * 9;
        for (int ci = 0; ci < CH; ci++) {
            #pragma unroll
            for (int r = 0; r < 3; r++) {
                #pragma unroll
                for (int s = 0; s < 3; s++) {
                    float v = xs[ci][r][wo + s];
                    dy += v * wyp[ci * 9 + r * 3 + s];
                    dx += v * wxp[ci * 9 + r * 3 + s];
                }
            }
        }
    }
    dy += ob[2 * ku];
    dx += ob[2 * ku + 1];

    float py = (float)(ho - 1 + ku / 3) + dy;
    float px = (float)(wo - 1 + ku % 3) + dx;
    float y0f = floorf(py), x0f = floorf(px);
    float4 prm;
    prm.x = __int_as_float((int)y0f);
    prm.y = __int_as_float((int)x0f);
    prm.z = py - y0f;
    prm.w = px - x0f;
    ((float4*)params)[((size_t)(b * KK + k)) * HW + ho * 64 + wo] = prm;
}

// ---------------- K2: fused gather + f16 MFMA GEMM
// block: 256 o x 128 p, 512 threads (8 waves of 64o x 64p), K-chunk 32
#define PAD40 40
__global__ __launch_bounds__(512) void deform_mfma_kernel(
    const float* __restrict__ xt, const f16* __restrict__ Wt2,
    const float* __restrict__ params, const float* __restrict__ cb,
    float* __restrict__ out)
{
    int bid = blockIdx.x;
    int b  = bid & 7;            // XCD-affine: all p-tiles of batch b on one XCD
    int p0 = (bid >> 3) * 128;
    int t  = threadIdx.x;
    int l  = t & 63;
    int wv = t >> 6;

    __shared__ f16 Wl[256][PAD40];   // 20 KB, row pad 40 f16 (80 B) -> conflict-free b128 reads
    __shared__ f16 St[128][PAD40];   // 10 KB

    f32x4 acc[4][4];
    #pragma unroll
    for (int i = 0; i < 4; i++)
        #pragma unroll
        for (int j = 0; j < 4; j++)
            acc[i][j] = (f32x4)0.f;

    const int cc2 = (t & 15) * 2;    // channel pair within chunk
    const int pg  = t >> 4;          // pixel group (4 pixels)
    const float* xtb = xt + (size_t)b * HW * C;
    const float4* params4 = (const float4*)params;

    const int wo = (wv >> 1) * 64;   // wave o-block
    const int wp = (wv & 1) * 64;    // wave p-block
    const int ln = l & 15;
    const int kh = (l >> 4) * 8;

    for (int ch = 0; ch < 72; ch++) {
        int k     = ch >> 3;
        int cbase = (ch & 7) * 32;

        __syncthreads();

        // stage W chunk: Wl[o][0..31] = Wt2[o][k*256+cbase ..]
        #pragma unroll
        for (int i = 0; i < 2; i++) {
            int f  = t + 512 * i;
            int o  = f >> 2;
            int cc = (f & 3) * 8;
            *(f16x8*)&Wl[o][cc] =
                *(const f16x8*)&Wt2[(size_t)o * KTOT + k * 256 + cbase + cc];
        }

        // stage S chunk: bilinear gather from channel-last x_t (coalesced)
        #pragma unroll
        for (int j = 0; j < 4; j++) {
            int p = pg * 4 + j;
            float4 prm = params4[((size_t)(b * KK + k)) * HW + p0 + p];
            int y0 = __float_as_int(prm.x);
            int x0 = __float_as_int(prm.y);
            float wy = prm.z, wx = prm.w;
            int y1 = y0 + 1, x1 = x0 + 1;
            bool vy0 = (y0 >= 0) & (y0 < H);
            bool vy1 = (y1 >= 0) & (y1 < H);
            bool vx0 = (x0 >= 0) & (x0 < W);
            bool vx1 = (x1 >= 0) & (x1 < W);
            float w00 = (vy0 & vx0) ? (1.f - wy) * (1.f - wx) : 0.f;
            float w01 = (vy0 & vx1) ? (1.f - wy) * wx : 0.f;
            float w10 = (vy1 & vx0) ? wy * (1.f - wx) : 0.f;
            float w11 = (vy1 & vx1) ? wy * wx : 0.f;
            int yc0 = min(max(y0, 0), H - 1), yc1 = min(max(y1, 0), H - 1);
            int xc0 = min(max(x0, 0), W - 1), xc1 = min(max(x1, 0), W - 1);
            int i00 = yc0 * W + xc0, i01 = yc0 * W + xc1;
            int i10 = yc1 * W + xc0, i11 = yc1 * W + xc1;

            float2 a00 = *(const float2*)&xtb[(size_t)i00 * C + cbase + cc2];
            float2 a01 = *(const float2*)&xtb[(size_t)i01 * C + cbase + cc2];
            float2 a10 = *(const float2*)&xtb[(size_t)i10 * C + cbase + cc2];
            float2 a11 = *(const float2*)&xtb[(size_t)i11 * C + cbase + cc2];
            float v0 = w00 * a00.x + w01 * a01.x + w10 * a10.x + w11 * a11.x;
            float v1 = w00 * a00.y + w01 * a01.y + w10 * a10.y + w11 * a11.y;
            St[p][cc2]     = (f16)v0;
            St[p][cc2 + 1] = (f16)v1;
        }

        __syncthreads();

        // MFMA: 4x4 fragments of 16x16, K=32
        f16x8 af[4], bf[4];
        #pragma unroll
        for (int mf = 0; mf < 4; mf++)
            af[mf] = *(const f16x8*)&Wl[wo + mf * 16 + ln][kh];
        #pragma unroll
        for (int nf = 0; nf < 4; nf++)
            bf[nf] = *(const f16x8*)&St[wp + nf * 16 + ln][kh];
        #pragma unroll
        for (int mf = 0; mf < 4; mf++)
            #pragma unroll
            for (int nf = 0; nf < 4; nf++)
                acc[mf][nf] = __builtin_amdgcn_mfma_f32_16x16x32_f16(
                    af[mf], bf[nf], acc[mf][nf], 0, 0, 0);
    }

    // epilogue: bias + store (D: row=(l>>4)*4+r -> o, col=l&15 -> p)
    #pragma unroll
    for (int mf = 0; mf < 4; mf++) {
        #pragma unroll
        for (int r = 0; r < 4; r++) {
            int o = wo + mf * 16 + (l >> 4) * 4 + r;
            float bias = cb[o];
            #pragma unroll
            for (int nf = 0; nf < 4; nf++) {
                int p = p0 + wp + nf * 16 + ln;
                out[((size_t)(b * O + o)) * HW + p] = acc[mf][nf][r] + bias;
            }
        }
    }
}

extern "C" void kernel_launch(void* const* d_in, const int* in_sizes, int n_in,
                              void* d_out, int out_size, void* d_ws, size_t ws_size,
                              hipStream_t stream) {
    const float* x  = (const float*)d_in[0];
    const float* ow = (const float*)d_in[1];
    const float* ob = (const float*)d_in[2];
    const float* cw = (const float*)d_in[3];
    const float* cb = (const float*)d_in[4];
    float* out = (float*)d_out;

    char* ws = (char*)d_ws;
    float* params = (float*)ws;                         // 8*9*4096*16 B   = 4,718,592
    f16*   Wt2    = (f16*)(ws + 4718592);               // 256*2304*2 B    = 1,179,648
    float* xt     = (float*)(ws + 4718592 + 1179648);   // 8*4096*256*4 B  = 33,554,432

    wconv_kernel<<<(O * KTOT + 255) / 256, 256, 0, stream>>>(cw, Wt2);
    transpose_x_kernel<<<dim3(64, 4, NB), 256, 0, stream>>>(x, xt);
    offset_conv_kernel<<<NB * 64, 576, 0, stream>>>(x, ow, ob, params);
    deform_mfma_kernel<<<256, 512, 0, stream>>>(xt, Wt2, params, cb, out);
}

// Round 3
// 196.052 us; speedup vs baseline: 3.9842x; 2.2692x over previous
//
#include <hip/hip_runtime.h>

#define H 64
#define W 64
#define C 256
#define O 256
#define NB 8
#define KK 9
#define HW 4096
#define KTOT 2304   // 9*256

typedef _Float16 f16;
typedef _Float16 f16x4 __attribute__((ext_vector_type(4)));
typedef _Float16 f16x8 __attribute__((ext_vector_type(8)));
typedef float f32x4 __attribute__((ext_vector_type(4)));

// ---------------- K0: conv_w (O,C,3,3) fp32 -> Wt2[o][k*256+c] f16
__global__ void wconv_kernel(const float* __restrict__ cw, f16* __restrict__ Wt2) {
    int tid = blockIdx.x * blockDim.x + threadIdx.x;  // o*2304 + k*256 + c
    if (tid >= O * KTOT) return;
    int o = tid / KTOT;
    int r = tid - o * KTOT;
    int k = r >> 8;
    int c = r & 255;
    Wt2[tid] = (f16)cw[o * KTOT + c * 9 + k];
}

// ---------------- transpose x (B,C,HW) fp32 -> x_t (B,HW,C) f16
__global__ __launch_bounds__(256) void transpose_x_kernel(
    const float* __restrict__ x, f16* __restrict__ xt)
{
    __shared__ float tile[64][65];
    int b   = blockIdx.z;
    int yx0 = blockIdx.x * 64;
    int c0  = blockIdx.y * 64;
    int t = threadIdx.x;
    int j = t & 63, q = t >> 6;
    #pragma unroll 4
    for (int i = 0; i < 16; i++) {
        int c = c0 + q * 16 + i;
        tile[q * 16 + i][j] = x[((size_t)(b * C + c)) * HW + yx0 + j];
    }
    __syncthreads();
    #pragma unroll 4
    for (int i = 0; i < 16; i++) {
        int yx = yx0 + q * 16 + i;
        xt[((size_t)(b * HW + yx)) * C + c0 + j] = (f16)tile[j][q * 16 + i];
    }
}

// ---------------- K1: offset conv (18 ch) + sampling-param precompute
#define CH 16
__global__ __launch_bounds__(576) void offset_conv_kernel(
    const float* __restrict__ x, const float* __restrict__ ow,
    const float* __restrict__ ob, float* __restrict__ params)
{
    int blk = blockIdx.x;
    int b  = blk >> 6;
    int ho = blk & 63;
    int t  = threadIdx.x;
    int k  = t >> 6;
    int wo = t & 63;
    int ku = __builtin_amdgcn_readfirstlane(k);

    __shared__ float xs[CH][3][66];

    float dy = 0.f, dx = 0.f;

    for (int c0 = 0; c0 < C; c0 += CH) {
        __syncthreads();
        for (int idx = t; idx < CH * 3 * 66; idx += 576) {
            int ci  = idx / 198;
            int rem = idx - ci * 198;
            int r   = rem / 66;
            int col = rem - r * 66;
            int row = ho - 1 + r;
            int xc  = col - 1;
            float v = 0.f;
            if (row >= 0 && row < H && xc >= 0 && xc < W)
                v = x[(((size_t)b * C + c0 + ci) * H + row) * W + xc];
            xs[ci][r][col] = v;
        }
        __syncthreads();
        const float* wyp = ow + (size_t)(2 * ku) * KTOT + (size_t)c0 * 9;
        const float* wxp = ow + (size_t)(2 * ku + 1) * KTOT + (size_t)c0 * 9;
        for (int ci = 0; ci < CH; ci++) {
            #pragma unroll
            for (int r = 0; r < 3; r++) {
                #pragma unroll
                for (int s = 0; s < 3; s++) {
                    float v = xs[ci][r][wo + s];
                    dy += v * wyp[ci * 9 + r * 3 + s];
                    dx += v * wxp[ci * 9 + r * 3 + s];
                }
            }
        }
    }
    dy += ob[2 * ku];
    dx += ob[2 * ku + 1];

    float py = (float)(ho - 1 + ku / 3) + dy;
    float px = (float)(wo - 1 + ku % 3) + dx;
    float y0f = floorf(py), x0f = floorf(px);
    float4 prm;
    prm.x = __int_as_float((int)y0f);
    prm.y = __int_as_float((int)x0f);
    prm.z = py - y0f;
    prm.w = px - x0f;
    ((float4*)params)[((size_t)(b * KK + k)) * HW + ho * 64 + wo] = prm;
}

// ---------------- K2: fused gather + f16 MFMA GEMM, T14-pipelined
// block: 256 o x 64 p, 512 threads (8 waves: 4 o-blocks x 2 p-blocks), K-chunk 32
#define PAD40 40
__global__ __launch_bounds__(512, 4) void deform_mfma_kernel(
    const f16* __restrict__ xt, const f16* __restrict__ Wt2,
    const float* __restrict__ params, const float* __restrict__ cb,
    float* __restrict__ out)
{
    int bid = blockIdx.x;
    int b  = bid & 7;            // XCD-affine: batch b -> XCD b; xt16 plane 2.1 MB L2-resident
    int p0 = (bid >> 3) * 64;
    int t  = threadIdx.x;
    int l  = t & 63;
    int wv = t >> 6;

    __shared__ f16 Wl[256][PAD40];   // 20 KB
    __shared__ f16 St[64][PAD40];    // 5 KB

    f32x4 acc[4][2];
    #pragma unroll
    for (int i = 0; i < 4; i++)
        #pragma unroll
        for (int j = 0; j < 2; j++)
            acc[i][j] = (f32x4)0.f;

    const int px  = t >> 3;          // pixel [0,64)
    const int cc4 = (t & 7) * 4;     // 4 channels within chunk
    const int wo1 = t >> 2;          // W staging row [0,128)
    const int wcc = (t & 3) * 8;     // W staging col
    const f16* xt16b = xt + (size_t)b * HW * C;
    const float4* params4 = (const float4*)params;

    const int wo = (wv >> 1) * 64;   // wave o-block
    const int wp = (wv & 1) * 32;    // wave p-block
    const int ln = l & 15;
    const int kh = (l >> 4) * 8;

    // per-k sampling state ("next")
    int i00n, i01n, i10n, i11n;
    float w00n, w01n, w10n, w11n;

#define RECOMP(kk_) do {                                                      \
    float4 prm = params4[((size_t)(b * KK + (kk_))) * HW + p0 + px];          \
    int y0 = __float_as_int(prm.x);                                           \
    int x0 = __float_as_int(prm.y);                                           \
    float wy = prm.z, wx = prm.w;                                             \
    int y1 = y0 + 1, x1 = x0 + 1;                                             \
    bool vy0 = (y0 >= 0) & (y0 < H);                                          \
    bool vy1 = (y1 >= 0) & (y1 < H);                                          \
    bool vx0 = (x0 >= 0) & (x0 < W);                                          \
    bool vx1 = (x1 >= 0) & (x1 < W);                                          \
    w00n = (vy0 & vx0) ? (1.f - wy) * (1.f - wx) : 0.f;                       \
    w01n = (vy0 & vx1) ? (1.f - wy) * wx : 0.f;                               \
    w10n = (vy1 & vx0) ? wy * (1.f - wx) : 0.f;                               \
    w11n = (vy1 & vx1) ? wy * wx : 0.f;                                       \
    int yc0 = min(max(y0, 0), H - 1), yc1 = min(max(y1, 0), H - 1);           \
    int xc0 = min(max(x0, 0), W - 1), xc1 = min(max(x1, 0), W - 1);           \
    i00n = yc0 * W + xc0; i01n = yc0 * W + xc1;                               \
    i10n = yc1 * W + xc0; i11n = yc1 * W + xc1;                               \
} while (0)

#define ISSUE(G0, G1, G2, G3, WA, WB, V00, V01, V10, V11, chn_) do {          \
    int kk_ = (chn_) >> 3; int cb_ = ((chn_) & 7) * 32;                       \
    const f16* xb_ = xt16b + cb_ + cc4;                                       \
    G0 = *(const f16x4*)(xb_ + (size_t)i00n * C);                             \
    G1 = *(const f16x4*)(xb_ + (size_t)i01n * C);                             \
    G2 = *(const f16x4*)(xb_ + (size_t)i10n * C);                             \
    G3 = *(const f16x4*)(xb_ + (size_t)i11n * C);                             \
    const f16* wb_ = Wt2 + (size_t)kk_ * 256 + cb_ + wcc;                     \
    WA = *(const f16x8*)(wb_ + (size_t)wo1 * KTOT);                           \
    WB = *(const f16x8*)(wb_ + (size_t)(wo1 + 128) * KTOT);                   \
    V00 = w00n; V01 = w01n; V10 = w10n; V11 = w11n;                           \
} while (0)

#define CONSUME(G0, G1, G2, G3, WA, WB, V00, V01, V10, V11) do {              \
    f16x4 st_;                                                                \
    st_[0] = (f16)(V00 * (float)G0[0] + V01 * (float)G1[0] +                  \
                   V10 * (float)G2[0] + V11 * (float)G3[0]);                  \
    st_[1] = (f16)(V00 * (float)G0[1] + V01 * (float)G1[1] +                  \
                   V10 * (float)G2[1] + V11 * (float)G3[1]);                  \
    st_[2] = (f16)(V00 * (float)G0[2] + V01 * (float)G1[2] +                  \
                   V10 * (float)G2[2] + V11 * (float)G3[2]);                  \
    st_[3] = (f16)(V00 * (float)G0[3] + V01 * (float)G1[3] +                  \
                   V10 * (float)G2[3] + V11 * (float)G3[3]);                  \
    *(f16x4*)&St[px][cc4] = st_;                                              \
    *(f16x8*)&Wl[wo1][wcc] = WA;                                              \
    *(f16x8*)&Wl[wo1 + 128][wcc] = WB;                                        \
} while (0)

#define DOMFMA() do {                                                         \
    f16x8 af0 = *(const f16x8*)&Wl[wo +  0 + ln][kh];                         \
    f16x8 af1 = *(const f16x8*)&Wl[wo + 16 + ln][kh];                         \
    f16x8 af2 = *(const f16x8*)&Wl[wo + 32 + ln][kh];                         \
    f16x8 af3 = *(const f16x8*)&Wl[wo + 48 + ln][kh];                         \
    f16x8 bf0 = *(const f16x8*)&St[wp +  0 + ln][kh];                         \
    f16x8 bf1 = *(const f16x8*)&St[wp + 16 + ln][kh];                         \
    acc[0][0] = __builtin_amdgcn_mfma_f32_16x16x32_f16(af0, bf0, acc[0][0], 0, 0, 0); \
    acc[0][1] = __builtin_amdgcn_mfma_f32_16x16x32_f16(af0, bf1, acc[0][1], 0, 0, 0); \
    acc[1][0] = __builtin_amdgcn_mfma_f32_16x16x32_f16(af1, bf0, acc[1][0], 0, 0, 0); \
    acc[1][1] = __builtin_amdgcn_mfma_f32_16x16x32_f16(af1, bf1, acc[1][1], 0, 0, 0); \
    acc[2][0] = __builtin_amdgcn_mfma_f32_16x16x32_f16(af2, bf0, acc[2][0], 0, 0, 0); \
    acc[2][1] = __builtin_amdgcn_mfma_f32_16x16x32_f16(af2, bf1, acc[2][1], 0, 0, 0); \
    acc[3][0] = __builtin_amdgcn_mfma_f32_16x16x32_f16(af3, bf0, acc[3][0], 0, 0, 0); \
    acc[3][1] = __builtin_amdgcn_mfma_f32_16x16x32_f16(af3, bf1, acc[3][1], 0, 0, 0); \
} while (0)

    // phase register sets
    f16x4 ga0, ga1, ga2, ga3, gb0, gb1, gb2, gb3;
    f16x8 wa0, wa1, wb0, wb1;
    float va00, va01, va10, va11, vb00, vb01, vb10, vb11;

    RECOMP(0);
    ISSUE(ga0, ga1, ga2, ga3, wa0, wa1, va00, va01, va10, va11, 0);

    for (int ch = 0; ch < 72; ch += 2) {
        // ---- step A: consume chunk ch, issue chunk ch+1 into B
        {
            int chn = ch + 1;
            if ((chn & 7) == 0) RECOMP(chn >> 3);
            ISSUE(gb0, gb1, gb2, gb3, wb0, wb1, vb00, vb01, vb10, vb11, chn);
        }
        __syncthreads();
        CONSUME(ga0, ga1, ga2, ga3, wa0, wa1, va00, va01, va10, va11);
        __syncthreads();
        DOMFMA();
        // ---- step B: consume chunk ch+1, issue chunk min(ch+2,71) into A
        {
            int chn = ch + 2 < 72 ? ch + 2 : 71;
            if ((chn & 7) == 0) RECOMP(chn >> 3);
            ISSUE(ga0, ga1, ga2, ga3, wa0, wa1, va00, va01, va10, va11, chn);
        }
        __syncthreads();
        CONSUME(gb0, gb1, gb2, gb3, wb0, wb1, vb00, vb01, vb10, vb11);
        __syncthreads();
        DOMFMA();
    }

    // epilogue: bias + store (D: row=(l>>4)*4+r -> o, col=l&15 -> p)
    #pragma unroll
    for (int mf = 0; mf < 4; mf++) {
        #pragma unroll
        for (int r = 0; r < 4; r++) {
            int o = wo + mf * 16 + (l >> 4) * 4 + r;
            float bias = cb[o];
            #pragma unroll
            for (int nf = 0; nf < 2; nf++) {
                int p = p0 + wp + nf * 16 + ln;
                out[((size_t)(b * O + o)) * HW + p] = acc[mf][nf][r] + bias;
            }
        }
    }
#undef RECOMP
#undef ISSUE
#undef CONSUME
#undef DOMFMA
}

extern "C" void kernel_launch(void* const* d_in, const int* in_sizes, int n_in,
                              void* d_out, int out_size, void* d_ws, size_t ws_size,
                              hipStream_t stream) {
    const float* x  = (const float*)d_in[0];
    const float* ow = (const float*)d_in[1];
    const float* ob = (const float*)d_in[2];
    const float* cw = (const float*)d_in[3];
    const float* cb = (const float*)d_in[4];
    float* out = (float*)d_out;

    char* ws = (char*)d_ws;
    float* params = (float*)ws;                         // 8*9*4096*16 B   = 4,718,592
    f16*   Wt2    = (f16*)(ws + 4718592);               // 256*2304*2 B    = 1,179,648
    f16*   xt16   = (f16*)(ws + 4718592 + 1179648);     // 8*4096*256*2 B  = 16,777,216

    wconv_kernel<<<(O * KTOT + 255) / 256, 256, 0, stream>>>(cw, Wt2);
    transpose_x_kernel<<<dim3(64, 4, NB), 256, 0, stream>>>(x, xt16);
    offset_conv_kernel<<<NB * 64, 576, 0, stream>>>(x, ow, ob, params);
    deform_mfma_kernel<<<512, 512, 0, stream>>>(xt16, Wt2, params, cb, out);
}

// Round 4
// 134.953 us; speedup vs baseline: 5.7880x; 1.4527x over previous
//
#include <hip/hip_runtime.h>

#define H 64
#define W 64
#define C 256
#define O 256
#define NB 8
#define KK 9
#define HW 4096
#define KTOT 2304   // 9*256

typedef _Float16 f16;
typedef _Float16 f16x8 __attribute__((ext_vector_type(8)));
typedef float f32x4 __attribute__((ext_vector_type(4)));

// ---------------- K0a: conv_w (O,C,3,3) fp32 -> Wt2[o][k*256+c] f16
__global__ void wconv_kernel(const float* __restrict__ cw, f16* __restrict__ Wt2) {
    int tid = blockIdx.x * blockDim.x + threadIdx.x;
    if (tid >= O * KTOT) return;
    int o = tid / KTOT;
    int r = tid - o * KTOT;
    int k = r >> 8;
    int c = r & 255;
    Wt2[tid] = (f16)cw[o * KTOT + c * 9 + k];
}

// ---------------- K0b: offset_w (18,256,3,3) -> Wo2[m][tap*256+c] f16, m padded to 32
__global__ void wo_prep_kernel(const float* __restrict__ ow, f16* __restrict__ Wo2) {
    int tid = blockIdx.x * blockDim.x + threadIdx.x;
    if (tid >= 32 * KTOT) return;
    int m = tid / KTOT;
    int r = tid - m * KTOT;
    int tap = r >> 8;
    int c = r & 255;
    Wo2[tid] = (m < 18) ? (f16)ow[(m * 256 + c) * 9 + tap] : (f16)0.f;
}

// ---------------- transpose x (B,C,HW) fp32 -> x_t (B,HW,C) f16
__global__ __launch_bounds__(256) void transpose_x_kernel(
    const float* __restrict__ x, f16* __restrict__ xt)
{
    __shared__ float tile[64][65];
    int b   = blockIdx.z;
    int yx0 = blockIdx.x * 64;
    int c0  = blockIdx.y * 64;
    int t = threadIdx.x;
    int j = t & 63, q = t >> 6;
    #pragma unroll 4
    for (int i = 0; i < 16; i++) {
        int c = c0 + q * 16 + i;
        tile[q * 16 + i][j] = x[((size_t)(b * C + c)) * HW + yx0 + j];
    }
    __syncthreads();
    #pragma unroll 4
    for (int i = 0; i < 16; i++) {
        int yx = yx0 + q * 16 + i;
        xt[((size_t)(b * HW + yx)) * C + c0 + j] = (f16)tile[j][q * 16 + i];
    }
}

// ---------------- K1: offset conv via direct-conv MFMA (M=32, 9 taps, shifted LDS reads)
// block: 128 px (2 image rows) x 32 m, 256 threads (4 waves of 32px x 32m)
__global__ __launch_bounds__(256, 4) void offset_mfma_kernel(
    const f16* __restrict__ xt, const f16* __restrict__ Wo2,
    const float* __restrict__ ob, float* __restrict__ params)
{
    int bid = blockIdx.x;
    int b  = bid & 7;
    int y0 = (bid >> 3) * 2;
    int t  = threadIdx.x;
    int l  = t & 63;
    int wv = t >> 6;
    const int ln = l & 15;
    const int kh = (l >> 4) * 8;

    __shared__ f16 xs[4][66][36];   // rows y0-1..y0+2, halo cols, 32c (pad 36)
    __shared__ f16 Ws[9][32][36];   // taps x m x 32c

    f32x4 acc[2][2];
    #pragma unroll
    for (int i = 0; i < 2; i++)
        #pragma unroll
        for (int j = 0; j < 2; j++) acc[i][j] = (f32x4)0.f;

    const f16* xtb = xt + (size_t)b * HW * C;

    for (int chunk = 0; chunk < 8; chunk++) {
        int cbase = chunk * 32;
        __syncthreads();
        // stage x tile (zero halo)
        for (int pos = t; pos < 264; pos += 256) {
            int row = pos / 66;
            int col = pos - row * 66;
            int y  = y0 - 1 + row;
            int xg = col - 1;
            f16x8 v0 = (f16x8)(f16)0.f, v1 = v0, v2 = v0, v3 = v0;
            if (y >= 0 && y < H && xg >= 0 && xg < W) {
                const f16* src = xtb + (size_t)(y * W + xg) * C + cbase;
                v0 = *(const f16x8*)(src);
                v1 = *(const f16x8*)(src + 8);
                v2 = *(const f16x8*)(src + 16);
                v3 = *(const f16x8*)(src + 24);
            }
            *(f16x8*)&xs[row][col][0]  = v0;
            *(f16x8*)&xs[row][col][8]  = v1;
            *(f16x8*)&xs[row][col][16] = v2;
            *(f16x8*)&xs[row][col][24] = v3;
        }
        // stage weights: 9*32*4 groups of 8
        for (int g = t; g < 1152; g += 256) {
            int tap = g >> 7;
            int rem = g & 127;
            int mm  = rem >> 2;
            int c8  = (rem & 3) * 8;
            *(f16x8*)&Ws[tap][mm][c8] =
                *(const f16x8*)&Wo2[(size_t)mm * KTOT + tap * 256 + cbase + c8];
        }
        __syncthreads();

        #pragma unroll
        for (int tap = 0; tap < 9; tap++) {
            const int tr = tap / 3, tc = tap % 3;
            f16x8 a0 = *(const f16x8*)&Ws[tap][ln][kh];
            f16x8 a1 = *(const f16x8*)&Ws[tap][16 + ln][kh];
            #pragma unroll
            for (int pf = 0; pf < 2; pf++) {
                int pxb = wv * 32 + pf * 16;
                int rl  = pxb >> 6;
                int cx  = (pxb & 63) + tc + ln;
                f16x8 bf = *(const f16x8*)&xs[rl + tr][cx][kh];
                acc[0][pf] = __builtin_amdgcn_mfma_f32_16x16x32_f16(a0, bf, acc[0][pf], 0, 0, 0);
                acc[1][pf] = __builtin_amdgcn_mfma_f32_16x16x32_f16(a1, bf, acc[1][pf], 0, 0, 0);
            }
        }
    }

    // epilogue: m=2k -> dy, m=2k+1 -> dx (same lane reg-quad), emit params
    int q = l >> 4;
    #pragma unroll
    for (int f = 0; f < 2; f++) {
        #pragma unroll
        for (int pr = 0; pr < 2; pr++) {
            int m0 = f * 16 + q * 4 + pr * 2;
            int k  = m0 >> 1;
            if (k > 8) continue;
            float oby = ob[m0];
            float obx = ob[m0 + 1];
            int tr = k / 3, tc = k - tr * 3;
            #pragma unroll
            for (int pf = 0; pf < 2; pf++) {
                int pxl = wv * 32 + pf * 16 + ln;
                int y   = y0 + (pxl >> 6);
                int xp  = pxl & 63;
                float dy = acc[f][pf][pr * 2]     + oby;
                float dx = acc[f][pf][pr * 2 + 1] + obx;
                float py  = (float)(y - 1 + tr) + dy;
                float pxx = (float)(xp - 1 + tc) + dx;
                float y0f = floorf(py), x0f = floorf(pxx);
                float4 prm;
                prm.x = __int_as_float((int)y0f);
                prm.y = __int_as_float((int)x0f);
                prm.z = py - y0f;
                prm.w = pxx - x0f;
                ((float4*)params)[((size_t)(b * KK + k)) * HW + y * W + xp] = prm;
            }
        }
    }
}

// ---------------- K2: fused gather + f16 MFMA GEMM
// block: 128 o x 128 px, 256 threads, 4 waves of 64o x 64px, K-chunk 32
#define PAD 36
__global__ __launch_bounds__(256, 2) void deform_mfma_kernel(
    const f16* __restrict__ xt, const f16* __restrict__ Wt2,
    const float* __restrict__ params, const float* __restrict__ cb,
    float* __restrict__ out)
{
    int bid = blockIdx.x;
    int b  = bid & 7;
    int r  = bid >> 3;
    int oh = (r & 1) * 128;
    int p0 = (r >> 1) * 128;
    int t  = threadIdx.x;
    int l  = t & 63;
    int wv = t >> 6;

    __shared__ f16 Wl[128][PAD];   // 9.2 KB
    __shared__ f16 St[128][PAD];   // 9.2 KB

    f32x4 acc[4][4];
    #pragma unroll
    for (int i = 0; i < 4; i++)
        #pragma unroll
        for (int j = 0; j < 4; j++) acc[i][j] = (f32x4)0.f;

    const int row2 = t >> 1;             // px row for S, o row for W
    const int ch16 = (t & 1) * 16;
    const f16* xtb  = xt + (size_t)b * HW * C;
    const f16* wrow = Wt2 + (size_t)(oh + row2) * KTOT + ch16;
    const float4* params4 = (const float4*)params;

    const int wo = (wv >> 1) * 64;
    const int wp = (wv & 1) * 64;
    const int ln = l & 15;
    const int kh = (l >> 4) * 8;

    int i00n, i01n, i10n, i11n;
    float w00n, w01n, w10n, w11n;

#define RECOMP(kk_) do {                                                      \
    float4 prm = params4[((size_t)(b * KK + (kk_))) * HW + p0 + row2];        \
    int y0 = __float_as_int(prm.x);                                           \
    int x0 = __float_as_int(prm.y);                                           \
    float wy = prm.z, wx = prm.w;                                             \
    int y1 = y0 + 1, x1 = x0 + 1;                                             \
    bool vy0 = (y0 >= 0) & (y0 < H);                                          \
    bool vy1 = (y1 >= 0) & (y1 < H);                                          \
    bool vx0 = (x0 >= 0) & (x0 < W);                                          \
    bool vx1 = (x1 >= 0) & (x1 < W);                                          \
    w00n = (vy0 & vx0) ? (1.f - wy) * (1.f - wx) : 0.f;                       \
    w01n = (vy0 & vx1) ? (1.f - wy) * wx : 0.f;                               \
    w10n = (vy1 & vx0) ? wy * (1.f - wx) : 0.f;                               \
    w11n = (vy1 & vx1) ? wy * wx : 0.f;                                       \
    int yc0 = min(max(y0, 0), H - 1), yc1 = min(max(y1, 0), H - 1);           \
    int xc0 = min(max(x0, 0), W - 1), xc1 = min(max(x1, 0), W - 1);           \
    i00n = yc0 * W + xc0; i01n = yc0 * W + xc1;                               \
    i10n = yc1 * W + xc0; i11n = yc1 * W + xc1;                               \
} while (0)

#define ISSUE(G0, G1, G2, G3, G4, G5, G6, G7, WA0, WA1,                       \
              V00, V01, V10, V11, chn_) do {                                  \
    int kk_ = (chn_) >> 3; int cb_ = ((chn_) & 7) * 32;                       \
    const f16* xb_ = xtb + cb_ + ch16;                                        \
    G0 = *(const f16x8*)(xb_ + (size_t)i00n * C);                             \
    G1 = *(const f16x8*)(xb_ + (size_t)i00n * C + 8);                         \
    G2 = *(const f16x8*)(xb_ + (size_t)i01n * C);                             \
    G3 = *(const f16x8*)(xb_ + (size_t)i01n * C + 8);                         \
    G4 = *(const f16x8*)(xb_ + (size_t)i10n * C);                             \
    G5 = *(const f16x8*)(xb_ + (size_t)i10n * C + 8);                         \
    G6 = *(const f16x8*)(xb_ + (size_t)i11n * C);                             \
    G7 = *(const f16x8*)(xb_ + (size_t)i11n * C + 8);                         \
    const f16* wb_ = wrow + (size_t)kk_ * 256 + cb_;                          \
    WA0 = *(const f16x8*)(wb_);                                               \
    WA1 = *(const f16x8*)(wb_ + 8);                                           \
    V00 = w00n; V01 = w01n; V10 = w10n; V11 = w11n;                           \
} while (0)

#define CONSUME(G0, G1, G2, G3, G4, G5, G6, G7, WA0, WA1,                     \
                V00, V01, V10, V11) do {                                      \
    f16 h00 = (f16)V00, h01 = (f16)V01, h10 = (f16)V10, h11 = (f16)V11;       \
    f16x8 r0 = G0 * h00 + G2 * h01 + G4 * h10 + G6 * h11;                     \
    f16x8 r1 = G1 * h00 + G3 * h01 + G5 * h10 + G7 * h11;                     \
    *(f16x8*)&St[row2][ch16]     = r0;                                        \
    *(f16x8*)&St[row2][ch16 + 8] = r1;                                        \
    *(f16x8*)&Wl[row2][ch16]     = WA0;                                       \
    *(f16x8*)&Wl[row2][ch16 + 8] = WA1;                                       \
} while (0)

#define DOMFMA() do {                                                         \
    f16x8 af0 = *(const f16x8*)&Wl[wo +  0 + ln][kh];                         \
    f16x8 af1 = *(const f16x8*)&Wl[wo + 16 + ln][kh];                         \
    f16x8 af2 = *(const f16x8*)&Wl[wo + 32 + ln][kh];                         \
    f16x8 af3 = *(const f16x8*)&Wl[wo + 48 + ln][kh];                         \
    f16x8 bf0 = *(const f16x8*)&St[wp +  0 + ln][kh];                         \
    f16x8 bf1 = *(const f16x8*)&St[wp + 16 + ln][kh];                         \
    f16x8 bf2 = *(const f16x8*)&St[wp + 32 + ln][kh];                         \
    f16x8 bf3 = *(const f16x8*)&St[wp + 48 + ln][kh];                         \
    acc[0][0] = __builtin_amdgcn_mfma_f32_16x16x32_f16(af0, bf0, acc[0][0], 0, 0, 0); \
    acc[0][1] = __builtin_amdgcn_mfma_f32_16x16x32_f16(af0, bf1, acc[0][1], 0, 0, 0); \
    acc[0][2] = __builtin_amdgcn_mfma_f32_16x16x32_f16(af0, bf2, acc[0][2], 0, 0, 0); \
    acc[0][3] = __builtin_amdgcn_mfma_f32_16x16x32_f16(af0, bf3, acc[0][3], 0, 0, 0); \
    acc[1][0] = __builtin_amdgcn_mfma_f32_16x16x32_f16(af1, bf0, acc[1][0], 0, 0, 0); \
    acc[1][1] = __builtin_amdgcn_mfma_f32_16x16x32_f16(af1, bf1, acc[1][1], 0, 0, 0); \
    acc[1][2] = __builtin_amdgcn_mfma_f32_16x16x32_f16(af1, bf2, acc[1][2], 0, 0, 0); \
    acc[1][3] = __builtin_amdgcn_mfma_f32_16x16x32_f16(af1, bf3, acc[1][3], 0, 0, 0); \
    acc[2][0] = __builtin_amdgcn_mfma_f32_16x16x32_f16(af2, bf0, acc[2][0], 0, 0, 0); \
    acc[2][1] = __builtin_amdgcn_mfma_f32_16x16x32_f16(af2, bf1, acc[2][1], 0, 0, 0); \
    acc[2][2] = __builtin_amdgcn_mfma_f32_16x16x32_f16(af2, bf2, acc[2][2], 0, 0, 0); \
    acc[2][3] = __builtin_amdgcn_mfma_f32_16x16x32_f16(af2, bf3, acc[2][3], 0, 0, 0); \
    acc[3][0] = __builtin_amdgcn_mfma_f32_16x16x32_f16(af3, bf0, acc[3][0], 0, 0, 0); \
    acc[3][1] = __builtin_amdgcn_mfma_f32_16x16x32_f16(af3, bf1, acc[3][1], 0, 0, 0); \
    acc[3][2] = __builtin_amdgcn_mfma_f32_16x16x32_f16(af3, bf2, acc[3][2], 0, 0, 0); \
    acc[3][3] = __builtin_amdgcn_mfma_f32_16x16x32_f16(af3, bf3, acc[3][3], 0, 0, 0); \
} while (0)

    f16x8 ga0, ga1, ga2, ga3, ga4, ga5, ga6, ga7;
    f16x8 gb0, gb1, gb2, gb3, gb4, gb5, gb6, gb7;
    f16x8 wa0, wa1, wb0, wb1;
    float va00, va01, va10, va11, vb00, vb01, vb10, vb11;

    RECOMP(0);
    ISSUE(ga0, ga1, ga2, ga3, ga4, ga5, ga6, ga7, wa0, wa1,
          va00, va01, va10, va11, 0);

    for (int ch = 0; ch < 72; ch += 2) {
        {
            int chn = ch + 1;
            if ((chn & 7) == 0) RECOMP(chn >> 3);
            ISSUE(gb0, gb1, gb2, gb3, gb4, gb5, gb6, gb7, wb0, wb1,
                  vb00, vb01, vb10, vb11, chn);
        }
        __syncthreads();
        CONSUME(ga0, ga1, ga2, ga3, ga4, ga5, ga6, ga7, wa0, wa1,
                va00, va01, va10, va11);
        __syncthreads();
        DOMFMA();
        {
            int chn = ch + 2 < 72 ? ch + 2 : 71;
            if ((chn & 7) == 0) RECOMP(chn >> 3);
            ISSUE(ga0, ga1, ga2, ga3, ga4, ga5, ga6, ga7, wa0, wa1,
                  va00, va01, va10, va11, chn);
        }
        __syncthreads();
        CONSUME(gb0, gb1, gb2, gb3, gb4, gb5, gb6, gb7, wb0, wb1,
                vb00, vb01, vb10, vb11);
        __syncthreads();
        DOMFMA();
    }

    // epilogue: bias + store (D: row=(l>>4)*4+r -> o, col=l&15 -> p)
    #pragma unroll
    for (int mf = 0; mf < 4; mf++) {
        #pragma unroll
        for (int rr = 0; rr < 4; rr++) {
            int o = oh + wo + mf * 16 + (l >> 4) * 4 + rr;
            float bias = cb[o];
            #pragma unroll
            for (int nf = 0; nf < 4; nf++) {
                int p = p0 + wp + nf * 16 + ln;
                out[((size_t)(b * O + o)) * HW + p] = acc[mf][nf][rr] + bias;
            }
        }
    }
#undef RECOMP
#undef ISSUE
#undef CONSUME
#undef DOMFMA
}

extern "C" void kernel_launch(void* const* d_in, const int* in_sizes, int n_in,
                              void* d_out, int out_size, void* d_ws, size_t ws_size,
                              hipStream_t stream) {
    const float* x  = (const float*)d_in[0];
    const float* ow = (const float*)d_in[1];
    const float* ob = (const float*)d_in[2];
    const float* cw = (const float*)d_in[3];
    const float* cb = (const float*)d_in[4];
    float* out = (float*)d_out;

    char* ws = (char*)d_ws;
    float* params = (float*)ws;                         // 4,718,592 B
    f16*   Wt2    = (f16*)(ws + 4718592);               // 1,179,648 B
    f16*   xt16   = (f16*)(ws + 4718592 + 1179648);     // 16,777,216 B
    f16*   Wo2    = (f16*)(ws + 4718592 + 1179648 + 16777216); // 147,456 B

    wconv_kernel<<<(O * KTOT + 255) / 256, 256, 0, stream>>>(cw, Wt2);
    wo_prep_kernel<<<(32 * KTOT + 255) / 256, 256, 0, stream>>>(ow, Wo2);
    transpose_x_kernel<<<dim3(64, 4, NB), 256, 0, stream>>>(x, xt16);
    offset_mfma_kernel<<<256, 256, 0, stream>>>(xt16, Wo2, ob, params);
    deform_mfma_kernel<<<512, 256, 0, stream>>>(xt16, Wt2, params, cb, out);
}

// Round 5
// 134.640 us; speedup vs baseline: 5.8014x; 1.0023x over previous
//
#include <hip/hip_runtime.h>

#define H 64
#define W 64
#define C 256
#define O 256
#define NB 8
#define KK 9
#define HW 4096
#define KTOT 2304   // 9*256

typedef _Float16 f16;
typedef _Float16 f16x8 __attribute__((ext_vector_type(8)));
typedef float f32x4 __attribute__((ext_vector_type(4)));

// raw barrier: no vmcnt drain (keeps global loads in flight across it)
#define BAR_FULL() do {                                            \
    __builtin_amdgcn_sched_barrier(0);                             \
    asm volatile("s_waitcnt lgkmcnt(0)" ::: "memory");             \
    __builtin_amdgcn_s_barrier();                                  \
    __builtin_amdgcn_sched_barrier(0);                             \
} while (0)
#define BAR_RAW() do {                                             \
    __builtin_amdgcn_sched_barrier(0);                             \
    asm volatile("" ::: "memory");                                 \
    __builtin_amdgcn_s_barrier();                                  \
    __builtin_amdgcn_sched_barrier(0);                             \
} while (0)

// ---------------- K0: fused weight prep
// conv_w (O,C,3,3) fp32 -> Wt2[o][k*256+c] f16 ; offset_w -> Wo2[m][tap*256+c], m pad 32
__global__ void wprep_kernel(const float* __restrict__ cw, const float* __restrict__ ow,
                             f16* __restrict__ Wt2, f16* __restrict__ Wo2) {
    int tid = blockIdx.x * blockDim.x + threadIdx.x;
    if (tid < O * KTOT) {
        int o = tid / KTOT;
        int r = tid - o * KTOT;
        int k = r >> 8;
        int c = r & 255;
        Wt2[tid] = (f16)cw[o * KTOT + c * 9 + k];
    } else if (tid < O * KTOT + 32 * KTOT) {
        int t2 = tid - O * KTOT;
        int m = t2 / KTOT;
        int r = t2 - m * KTOT;
        int tap = r >> 8;
        int c = r & 255;
        Wo2[t2] = (m < 18) ? (f16)ow[(m * 256 + c) * 9 + tap] : (f16)0.f;
    }
}

// ---------------- transpose x (B,C,HW) fp32 -> x_t (B,HW,C) f16
__global__ __launch_bounds__(256) void transpose_x_kernel(
    const float* __restrict__ x, f16* __restrict__ xt)
{
    __shared__ float tile[64][65];
    int b   = blockIdx.z;
    int yx0 = blockIdx.x * 64;
    int c0  = blockIdx.y * 64;
    int t = threadIdx.x;
    int j = t & 63, q = t >> 6;
    #pragma unroll 4
    for (int i = 0; i < 16; i++) {
        int c = c0 + q * 16 + i;
        tile[q * 16 + i][j] = x[((size_t)(b * C + c)) * HW + yx0 + j];
    }
    __syncthreads();
    #pragma unroll 4
    for (int i = 0; i < 16; i++) {
        int yx = yx0 + q * 16 + i;
        xt[((size_t)(b * HW + yx)) * C + c0 + j] = (f16)tile[j][q * 16 + i];
    }
}

// ---------------- K1: offset conv via direct-conv MFMA (M=32, 9 taps, shifted LDS reads)
__global__ __launch_bounds__(256, 4) void offset_mfma_kernel(
    const f16* __restrict__ xt, const f16* __restrict__ Wo2,
    const float* __restrict__ ob, float* __restrict__ params)
{
    int bid = blockIdx.x;
    int b  = bid & 7;
    int y0 = (bid >> 3) * 2;
    int t  = threadIdx.x;
    int l  = t & 63;
    int wv = t >> 6;
    const int ln = l & 15;
    const int kh = (l >> 4) * 8;

    __shared__ f16 xs[4][66][36];
    __shared__ f16 Ws[9][32][36];

    f32x4 acc[2][2];
    #pragma unroll
    for (int i = 0; i < 2; i++)
        #pragma unroll
        for (int j = 0; j < 2; j++) acc[i][j] = (f32x4)0.f;

    const f16* xtb = xt + (size_t)b * HW * C;

    for (int chunk = 0; chunk < 8; chunk++) {
        int cbase = chunk * 32;
        BAR_RAW();
        for (int pos = t; pos < 264; pos += 256) {
            int row = pos / 66;
            int col = pos - row * 66;
            int y  = y0 - 1 + row;
            int xg = col - 1;
            f16x8 v0 = (f16x8)(f16)0.f, v1 = v0, v2 = v0, v3 = v0;
            if (y >= 0 && y < H && xg >= 0 && xg < W) {
                const f16* src = xtb + (size_t)(y * W + xg) * C + cbase;
                v0 = *(const f16x8*)(src);
                v1 = *(const f16x8*)(src + 8);
                v2 = *(const f16x8*)(src + 16);
                v3 = *(const f16x8*)(src + 24);
            }
            *(f16x8*)&xs[row][col][0]  = v0;
            *(f16x8*)&xs[row][col][8]  = v1;
            *(f16x8*)&xs[row][col][16] = v2;
            *(f16x8*)&xs[row][col][24] = v3;
        }
        for (int g = t; g < 1152; g += 256) {
            int tap = g >> 7;
            int rem = g & 127;
            int mm  = rem >> 2;
            int c8  = (rem & 3) * 8;
            *(f16x8*)&Ws[tap][mm][c8] =
                *(const f16x8*)&Wo2[(size_t)mm * KTOT + tap * 256 + cbase + c8];
        }
        BAR_FULL();

        #pragma unroll
        for (int tap = 0; tap < 9; tap++) {
            const int tr = tap / 3, tc = tap % 3;
            f16x8 a0 = *(const f16x8*)&Ws[tap][ln][kh];
            f16x8 a1 = *(const f16x8*)&Ws[tap][16 + ln][kh];
            #pragma unroll
            for (int pf = 0; pf < 2; pf++) {
                int pxb = wv * 32 + pf * 16;
                int rl  = pxb >> 6;
                int cx  = (pxb & 63) + tc + ln;
                f16x8 bf = *(const f16x8*)&xs[rl + tr][cx][kh];
                acc[0][pf] = __builtin_amdgcn_mfma_f32_16x16x32_f16(a0, bf, acc[0][pf], 0, 0, 0);
                acc[1][pf] = __builtin_amdgcn_mfma_f32_16x16x32_f16(a1, bf, acc[1][pf], 0, 0, 0);
            }
        }
    }

    int q = l >> 4;
    #pragma unroll
    for (int f = 0; f < 2; f++) {
        #pragma unroll
        for (int pr = 0; pr < 2; pr++) {
            int m0 = f * 16 + q * 4 + pr * 2;
            int k  = m0 >> 1;
            if (k > 8) continue;
            float oby = ob[m0];
            float obx = ob[m0 + 1];
            int tr = k / 3, tc = k - tr * 3;
            #pragma unroll
            for (int pf = 0; pf < 2; pf++) {
                int pxl = wv * 32 + pf * 16 + ln;
                int y   = y0 + (pxl >> 6);
                int xp  = pxl & 63;
                float dy = acc[f][pf][pr * 2]     + oby;
                float dx = acc[f][pf][pr * 2 + 1] + obx;
                float py  = (float)(y - 1 + tr) + dy;
                float pxx = (float)(xp - 1 + tc) + dx;
                float y0f = floorf(py), x0f = floorf(pxx);
                float4 prm;
                prm.x = __int_as_float((int)y0f);
                prm.y = __int_as_float((int)x0f);
                prm.z = py - y0f;
                prm.w = pxx - x0f;
                ((float4*)params)[((size_t)(b * KK + k)) * HW + y * W + xp] = prm;
            }
        }
    }
}

// ---------------- K2: fused gather + f16 MFMA GEMM, raw-barrier pipeline + LDS dbuf
// block: 128 o x 128 px, 256 threads, 4 waves of 64o x 64px, K-chunk 32
#define PAD 36
__global__ __launch_bounds__(256, 2) void deform_mfma_kernel(
    const f16* __restrict__ xt, const f16* __restrict__ Wt2,
    const float* __restrict__ params, const float* __restrict__ cb,
    float* __restrict__ out)
{
    int bid = blockIdx.x;
    int b  = bid & 7;
    int r  = bid >> 3;
    int oh = (r & 1) * 128;
    int p0 = (r >> 1) * 128;
    int t  = threadIdx.x;
    int l  = t & 63;
    int wv = t >> 6;

    __shared__ f16 Wl[2][128][PAD];   // 18.4 KB
    __shared__ f16 St[2][128][PAD];   // 18.4 KB

    f32x4 acc[4][4];
    #pragma unroll
    for (int i = 0; i < 4; i++)
        #pragma unroll
        for (int j = 0; j < 4; j++) acc[i][j] = (f32x4)0.f;

    const int row2 = t >> 1;
    const int ch16 = (t & 1) * 16;
    const f16* xtb  = xt + (size_t)b * HW * C;
    const f16* wrow = Wt2 + (size_t)(oh + row2) * KTOT + ch16;
    const float4* params4 = (const float4*)params;

    const int wo = (wv >> 1) * 64;
    const int wp = (wv & 1) * 64;
    const int ln = l & 15;
    const int kh = (l >> 4) * 8;

    int i00n, i01n, i10n, i11n;
    float w00n, w01n, w10n, w11n;

#define RECOMP(kk_) do {                                                      \
    float4 prm = params4[((size_t)(b * KK + (kk_))) * HW + p0 + row2];        \
    int y0 = __float_as_int(prm.x);                                           \
    int x0 = __float_as_int(prm.y);                                           \
    float wy = prm.z, wx = prm.w;                                             \
    int y1 = y0 + 1, x1 = x0 + 1;                                             \
    bool vy0 = (y0 >= 0) & (y0 < H);                                          \
    bool vy1 = (y1 >= 0) & (y1 < H);                                          \
    bool vx0 = (x0 >= 0) & (x0 < W);                                          \
    bool vx1 = (x1 >= 0) & (x1 < W);                                          \
    w00n = (vy0 & vx0) ? (1.f - wy) * (1.f - wx) : 0.f;                       \
    w01n = (vy0 & vx1) ? (1.f - wy) * wx : 0.f;                               \
    w10n = (vy1 & vx0) ? wy * (1.f - wx) : 0.f;                               \
    w11n = (vy1 & vx1) ? wy * wx : 0.f;                                       \
    int yc0 = min(max(y0, 0), H - 1), yc1 = min(max(y1, 0), H - 1);           \
    int xc0 = min(max(x0, 0), W - 1), xc1 = min(max(x1, 0), W - 1);           \
    i00n = yc0 * W + xc0; i01n = yc0 * W + xc1;                               \
    i10n = yc1 * W + xc0; i11n = yc1 * W + xc1;                               \
} while (0)

#define ISSUE(G0, G1, G2, G3, G4, G5, G6, G7, WA0, WA1,                       \
              V00, V01, V10, V11, chn_) do {                                  \
    int kk_ = (chn_) >> 3; int cb_ = ((chn_) & 7) * 32;                       \
    const f16* xb_ = xtb + cb_ + ch16;                                        \
    G0 = *(const f16x8*)(xb_ + (size_t)i00n * C);                             \
    G1 = *(const f16x8*)(xb_ + (size_t)i00n * C + 8);                         \
    G2 = *(const f16x8*)(xb_ + (size_t)i01n * C);                             \
    G3 = *(const f16x8*)(xb_ + (size_t)i01n * C + 8);                         \
    G4 = *(const f16x8*)(xb_ + (size_t)i10n * C);                             \
    G5 = *(const f16x8*)(xb_ + (size_t)i10n * C + 8);                         \
    G6 = *(const f16x8*)(xb_ + (size_t)i11n * C);                             \
    G7 = *(const f16x8*)(xb_ + (size_t)i11n * C + 8);                         \
    const f16* wb_ = wrow + (size_t)kk_ * 256 + cb_;                          \
    WA0 = *(const f16x8*)(wb_);                                               \
    WA1 = *(const f16x8*)(wb_ + 8);                                           \
    V00 = w00n; V01 = w01n; V10 = w10n; V11 = w11n;                           \
} while (0)

#define CONSUME(G0, G1, G2, G3, G4, G5, G6, G7, WA0, WA1,                     \
                V00, V01, V10, V11, buf_) do {                                \
    f16 h00 = (f16)V00, h01 = (f16)V01, h10 = (f16)V10, h11 = (f16)V11;       \
    f16x8 r0 = G0 * h00 + G2 * h01 + G4 * h10 + G6 * h11;                     \
    f16x8 r1 = G1 * h00 + G3 * h01 + G5 * h10 + G7 * h11;                     \
    *(f16x8*)&St[buf_][row2][ch16]     = r0;                                  \
    *(f16x8*)&St[buf_][row2][ch16 + 8] = r1;                                  \
    *(f16x8*)&Wl[buf_][row2][ch16]     = WA0;                                 \
    *(f16x8*)&Wl[buf_][row2][ch16 + 8] = WA1;                                 \
} while (0)

#define DOMFMA(buf_) do {                                                     \
    f16x8 af0 = *(const f16x8*)&Wl[buf_][wo +  0 + ln][kh];                   \
    f16x8 af1 = *(const f16x8*)&Wl[buf_][wo + 16 + ln][kh];                   \
    f16x8 af2 = *(const f16x8*)&Wl[buf_][wo + 32 + ln][kh];                   \
    f16x8 af3 = *(const f16x8*)&Wl[buf_][wo + 48 + ln][kh];                   \
    f16x8 bf0 = *(const f16x8*)&St[buf_][wp +  0 + ln][kh];                   \
    f16x8 bf1 = *(const f16x8*)&St[buf_][wp + 16 + ln][kh];                   \
    f16x8 bf2 = *(const f16x8*)&St[buf_][wp + 32 + ln][kh];                   \
    f16x8 bf3 = *(const f16x8*)&St[buf_][wp + 48 + ln][kh];                   \
    acc[0][0] = __builtin_amdgcn_mfma_f32_16x16x32_f16(af0, bf0, acc[0][0], 0, 0, 0); \
    acc[0][1] = __builtin_amdgcn_mfma_f32_16x16x32_f16(af0, bf1, acc[0][1], 0, 0, 0); \
    acc[0][2] = __builtin_amdgcn_mfma_f32_16x16x32_f16(af0, bf2, acc[0][2], 0, 0, 0); \
    acc[0][3] = __builtin_amdgcn_mfma_f32_16x16x32_f16(af0, bf3, acc[0][3], 0, 0, 0); \
    acc[1][0] = __builtin_amdgcn_mfma_f32_16x16x32_f16(af1, bf0, acc[1][0], 0, 0, 0); \
    acc[1][1] = __builtin_amdgcn_mfma_f32_16x16x32_f16(af1, bf1, acc[1][1], 0, 0, 0); \
    acc[1][2] = __builtin_amdgcn_mfma_f32_16x16x32_f16(af1, bf2, acc[1][2], 0, 0, 0); \
    acc[1][3] = __builtin_amdgcn_mfma_f32_16x16x32_f16(af1, bf3, acc[1][3], 0, 0, 0); \
    acc[2][0] = __builtin_amdgcn_mfma_f32_16x16x32_f16(af2, bf0, acc[2][0], 0, 0, 0); \
    acc[2][1] = __builtin_amdgcn_mfma_f32_16x16x32_f16(af2, bf1, acc[2][1], 0, 0, 0); \
    acc[2][2] = __builtin_amdgcn_mfma_f32_16x16x32_f16(af2, bf2, acc[2][2], 0, 0, 0); \
    acc[2][3] = __builtin_amdgcn_mfma_f32_16x16x32_f16(af2, bf3, acc[2][3], 0, 0, 0); \
    acc[3][0] = __builtin_amdgcn_mfma_f32_16x16x32_f16(af3, bf0, acc[3][0], 0, 0, 0); \
    acc[3][1] = __builtin_amdgcn_mfma_f32_16x16x32_f16(af3, bf1, acc[3][1], 0, 0, 0); \
    acc[3][2] = __builtin_amdgcn_mfma_f32_16x16x32_f16(af3, bf2, acc[3][2], 0, 0, 0); \
    acc[3][3] = __builtin_amdgcn_mfma_f32_16x16x32_f16(af3, bf3, acc[3][3], 0, 0, 0); \
} while (0)

    f16x8 ga0, ga1, ga2, ga3, ga4, ga5, ga6, ga7;
    f16x8 gb0, gb1, gb2, gb3, gb4, gb5, gb6, gb7;
    f16x8 wa0, wa1, wb0, wb1;
    float va00, va01, va10, va11, vb00, vb01, vb10, vb11;

    RECOMP(0);
    ISSUE(ga0, ga1, ga2, ga3, ga4, ga5, ga6, ga7, wa0, wa1,
          va00, va01, va10, va11, 0);

    for (int ch = 0; ch < 72; ch += 2) {
        {
            int chn = ch + 1;
            if ((chn & 7) == 0) RECOMP(chn >> 3);
            ISSUE(gb0, gb1, gb2, gb3, gb4, gb5, gb6, gb7, wb0, wb1,
                  vb00, vb01, vb10, vb11, chn);
        }
        CONSUME(ga0, ga1, ga2, ga3, ga4, ga5, ga6, ga7, wa0, wa1,
                va00, va01, va10, va11, 0);
        BAR_FULL();
        DOMFMA(0);
        {
            int chn = ch + 2 < 72 ? ch + 2 : 71;
            if ((chn & 7) == 0) RECOMP(chn >> 3);
            ISSUE(ga0, ga1, ga2, ga3, ga4, ga5, ga6, ga7, wa0, wa1,
                  va00, va01, va10, va11, chn);
        }
        CONSUME(gb0, gb1, gb2, gb3, gb4, gb5, gb6, gb7, wb0, wb1,
                vb00, vb01, vb10, vb11, 1);
        BAR_FULL();
        DOMFMA(1);
    }

    #pragma unroll
    for (int mf = 0; mf < 4; mf++) {
        #pragma unroll
        for (int rr = 0; rr < 4; rr++) {
            int o = oh + wo + mf * 16 + (l >> 4) * 4 + rr;
            float bias = cb[o];
            #pragma unroll
            for (int nf = 0; nf < 4; nf++) {
                int p = p0 + wp + nf * 16 + ln;
                out[((size_t)(b * O + o)) * HW + p] = acc[mf][nf][rr] + bias;
            }
        }
    }
#undef RECOMP
#undef ISSUE
#undef CONSUME
#undef DOMFMA
}

extern "C" void kernel_launch(void* const* d_in, const int* in_sizes, int n_in,
                              void* d_out, int out_size, void* d_ws, size_t ws_size,
                              hipStream_t stream) {
    const float* x  = (const float*)d_in[0];
    const float* ow = (const float*)d_in[1];
    const float* ob = (const float*)d_in[2];
    const float* cw = (const float*)d_in[3];
    const float* cb = (const float*)d_in[4];
    float* out = (float*)d_out;

    char* ws = (char*)d_ws;
    float* params = (float*)ws;                         // 4,718,592 B
    f16*   Wt2    = (f16*)(ws + 4718592);               // 1,179,648 B
    f16*   xt16   = (f16*)(ws + 4718592 + 1179648);     // 16,777,216 B
    f16*   Wo2    = (f16*)(ws + 4718592 + 1179648 + 16777216); // 147,456 B

    wprep_kernel<<<(O * KTOT + 32 * KTOT + 255) / 256, 256, 0, stream>>>(cw, ow, Wt2, Wo2);
    transpose_x_kernel<<<dim3(64, 4, NB), 256, 0, stream>>>(x, xt16);
    offset_mfma_kernel<<<256, 256, 0, stream>>>(xt16, Wo2, ob, params);
    deform_mfma_kernel<<<512, 256, 0, stream>>>(xt16, Wt2, params, cb, out);
}

// Round 6
// 129.081 us; speedup vs baseline: 6.0513x; 1.0431x over previous
//
#include <hip/hip_runtime.h>

#define H 64
#define W 64
#define C 256
#define O 256
#define NB 8
#define KK 9
#define HW 4096
#define KTOT 2304   // 9*256

typedef _Float16 f16;
typedef _Float16 f16x8 __attribute__((ext_vector_type(8)));
typedef float f32x4 __attribute__((ext_vector_type(4)));

// barrier with LDS-only drain (global loads stay in flight)
#define BAR_FULL() do {                                            \
    __builtin_amdgcn_sched_barrier(0);                             \
    asm volatile("s_waitcnt lgkmcnt(0)" ::: "memory");             \
    __builtin_amdgcn_s_barrier();                                  \
    __builtin_amdgcn_sched_barrier(0);                             \
} while (0)
#define BAR_RAW() do {                                             \
    __builtin_amdgcn_sched_barrier(0);                             \
    asm volatile("" ::: "memory");                                 \
    __builtin_amdgcn_s_barrier();                                  \
    __builtin_amdgcn_sched_barrier(0);                             \
} while (0)

// ---------------- K0: fused weight prep
__global__ void wprep_kernel(const float* __restrict__ cw, const float* __restrict__ ow,
                             f16* __restrict__ Wt2, f16* __restrict__ Wo2) {
    int tid = blockIdx.x * blockDim.x + threadIdx.x;
    if (tid < O * KTOT) {
        int o = tid / KTOT;
        int r = tid - o * KTOT;
        int k = r >> 8;
        int c = r & 255;
        Wt2[tid] = (f16)cw[o * KTOT + c * 9 + k];
    } else if (tid < O * KTOT + 32 * KTOT) {
        int t2 = tid - O * KTOT;
        int m = t2 / KTOT;
        int r = t2 - m * KTOT;
        int tap = r >> 8;
        int c = r & 255;
        Wo2[t2] = (m < 18) ? (f16)ow[(m * 256 + c) * 9 + tap] : (f16)0.f;
    }
}

// ---------------- transpose x (B,C,HW) fp32 -> x_t (B,HW,C) f16
__global__ __launch_bounds__(256) void transpose_x_kernel(
    const float* __restrict__ x, f16* __restrict__ xt)
{
    __shared__ float tile[64][65];
    int b   = blockIdx.z;
    int yx0 = blockIdx.x * 64;
    int c0  = blockIdx.y * 64;
    int t = threadIdx.x;
    int j = t & 63, q = t >> 6;
    #pragma unroll 4
    for (int i = 0; i < 16; i++) {
        int c = c0 + q * 16 + i;
        tile[q * 16 + i][j] = x[((size_t)(b * C + c)) * HW + yx0 + j];
    }
    __syncthreads();
    #pragma unroll 4
    for (int i = 0; i < 16; i++) {
        int yx = yx0 + q * 16 + i;
        xt[((size_t)(b * HW + yx)) * C + c0 + j] = (f16)tile[j][q * 16 + i];
    }
}

// ---------------- K1: offset conv via direct-conv MFMA (unchanged from R5)
__global__ __launch_bounds__(256, 4) void offset_mfma_kernel(
    const f16* __restrict__ xt, const f16* __restrict__ Wo2,
    const float* __restrict__ ob, float* __restrict__ params)
{
    int bid = blockIdx.x;
    int b  = bid & 7;
    int y0 = (bid >> 3) * 2;
    int t  = threadIdx.x;
    int l  = t & 63;
    int wv = t >> 6;
    const int ln = l & 15;
    const int kh = (l >> 4) * 8;

    __shared__ f16 xs[4][66][36];
    __shared__ f16 Ws[9][32][36];

    f32x4 acc[2][2];
    #pragma unroll
    for (int i = 0; i < 2; i++)
        #pragma unroll
        for (int j = 0; j < 2; j++) acc[i][j] = (f32x4)0.f;

    const f16* xtb = xt + (size_t)b * HW * C;

    for (int chunk = 0; chunk < 8; chunk++) {
        int cbase = chunk * 32;
        BAR_RAW();
        for (int pos = t; pos < 264; pos += 256) {
            int row = pos / 66;
            int col = pos - row * 66;
            int y  = y0 - 1 + row;
            int xg = col - 1;
            f16x8 v0 = (f16x8)(f16)0.f, v1 = v0, v2 = v0, v3 = v0;
            if (y >= 0 && y < H && xg >= 0 && xg < W) {
                const f16* src = xtb + (size_t)(y * W + xg) * C + cbase;
                v0 = *(const f16x8*)(src);
                v1 = *(const f16x8*)(src + 8);
                v2 = *(const f16x8*)(src + 16);
                v3 = *(const f16x8*)(src + 24);
            }
            *(f16x8*)&xs[row][col][0]  = v0;
            *(f16x8*)&xs[row][col][8]  = v1;
            *(f16x8*)&xs[row][col][16] = v2;
            *(f16x8*)&xs[row][col][24] = v3;
        }
        for (int g = t; g < 1152; g += 256) {
            int tap = g >> 7;
            int rem = g & 127;
            int mm  = rem >> 2;
            int c8  = (rem & 3) * 8;
            *(f16x8*)&Ws[tap][mm][c8] =
                *(const f16x8*)&Wo2[(size_t)mm * KTOT + tap * 256 + cbase + c8];
        }
        BAR_FULL();

        #pragma unroll
        for (int tap = 0; tap < 9; tap++) {
            const int tr = tap / 3, tc = tap % 3;
            f16x8 a0 = *(const f16x8*)&Ws[tap][ln][kh];
            f16x8 a1 = *(const f16x8*)&Ws[tap][16 + ln][kh];
            #pragma unroll
            for (int pf = 0; pf < 2; pf++) {
                int pxb = wv * 32 + pf * 16;
                int rl  = pxb >> 6;
                int cx  = (pxb & 63) + tc + ln;
                f16x8 bf = *(const f16x8*)&xs[rl + tr][cx][kh];
                acc[0][pf] = __builtin_amdgcn_mfma_f32_16x16x32_f16(a0, bf, acc[0][pf], 0, 0, 0);
                acc[1][pf] = __builtin_amdgcn_mfma_f32_16x16x32_f16(a1, bf, acc[1][pf], 0, 0, 0);
            }
        }
    }

    int q = l >> 4;
    #pragma unroll
    for (int f = 0; f < 2; f++) {
        #pragma unroll
        for (int pr = 0; pr < 2; pr++) {
            int m0 = f * 16 + q * 4 + pr * 2;
            int k  = m0 >> 1;
            if (k > 8) continue;
            float oby = ob[m0];
            float obx = ob[m0 + 1];
            int tr = k / 3, tc = k - tr * 3;
            #pragma unroll
            for (int pf = 0; pf < 2; pf++) {
                int pxl = wv * 32 + pf * 16 + ln;
                int y   = y0 + (pxl >> 6);
                int xp  = pxl & 63;
                float dy = acc[f][pf][pr * 2]     + oby;
                float dx = acc[f][pf][pr * 2 + 1] + obx;
                float py  = (float)(y - 1 + tr) + dy;
                float pxx = (float)(xp - 1 + tc) + dx;
                float y0f = floorf(py), x0f = floorf(pxx);
                float4 prm;
                prm.x = __int_as_float((int)y0f);
                prm.y = __int_as_float((int)x0f);
                prm.z = py - y0f;
                prm.w = pxx - x0f;
                ((float4*)params)[((size_t)(b * KK + k)) * HW + y * W + xp] = prm;
            }
        }
    }
}

// ---------------- K2: fused gather + f16 MFMA GEMM
// tile: 256 o x 64 px, 256 threads (4 waves, each 64o x 64px), K-chunk 32
// gather: 4 lanes per pixel (64B/corner, fully-consumed lines)
// W fragments: direct global->register (L2-resident), no LDS
#define SPAD 36
__global__ __launch_bounds__(256, 2) void deform_mfma_kernel(
    const f16* __restrict__ xt, const f16* __restrict__ Wt2,
    const float* __restrict__ params, const float* __restrict__ cb,
    float* __restrict__ out)
{
    int bid = blockIdx.x;
    int b  = bid & 7;              // XCD-affine batch
    int p0 = (bid >> 3) * 64;
    int t  = threadIdx.x;
    int l  = t & 63;
    int wv = t >> 6;

    __shared__ f16 St[2][64][SPAD];   // 9.2 KB total

    f32x4 acc[4][4];
    #pragma unroll
    for (int i = 0; i < 4; i++)
        #pragma unroll
        for (int j = 0; j < 4; j++) acc[i][j] = (f32x4)0.f;

    const int px  = t >> 2;          // pixel [0,64)
    const int cg  = (t & 3) * 8;     // channel group within 32-chunk
    const f16* xtb = xt + (size_t)b * HW * C;
    const float4* params4 = (const float4*)params;

    const int wo = wv * 64;          // wave o-block
    const int ln = l & 15;
    const int kh = (l >> 4) * 8;
    const f16* wbase = Wt2 + (size_t)(wo + ln) * KTOT + (l >> 4) * 8;

    int i00n, i01n, i10n, i11n;
    float w00n, w01n, w10n, w11n;

#define RECOMP(kk_) do {                                                      \
    float4 prm = params4[((size_t)(b * KK + (kk_))) * HW + p0 + px];          \
    int y0 = __float_as_int(prm.x);                                           \
    int x0 = __float_as_int(prm.y);                                           \
    float wy = prm.z, wx = prm.w;                                             \
    int y1 = y0 + 1, x1 = x0 + 1;                                             \
    bool vy0 = (y0 >= 0) & (y0 < H);                                          \
    bool vy1 = (y1 >= 0) & (y1 < H);                                          \
    bool vx0 = (x0 >= 0) & (x0 < W);                                          \
    bool vx1 = (x1 >= 0) & (x1 < W);                                          \
    w00n = (vy0 & vx0) ? (1.f - wy) * (1.f - wx) : 0.f;                       \
    w01n = (vy0 & vx1) ? (1.f - wy) * wx : 0.f;                               \
    w10n = (vy1 & vx0) ? wy * (1.f - wx) : 0.f;                               \
    w11n = (vy1 & vx1) ? wy * wx : 0.f;                                       \
    int yc0 = min(max(y0, 0), H - 1), yc1 = min(max(y1, 0), H - 1);           \
    int xc0 = min(max(x0, 0), W - 1), xc1 = min(max(x1, 0), W - 1);           \
    i00n = yc0 * W + xc0; i01n = yc0 * W + xc1;                               \
    i10n = yc1 * W + xc0; i11n = yc1 * W + xc1;                               \
} while (0)

// gather 4 corners (8 ch each) + 4 W fragments for chunk chn_
#define ISSUE(G00, G01, G10, G11, W0, W1, W2, W3,                             \
              V00, V01, V10, V11, chn_) do {                                  \
    int kk_ = (chn_) >> 3; int cb_ = ((chn_) & 7) * 32;                       \
    const f16* xb_ = xtb + cb_ + cg;                                          \
    G00 = *(const f16x8*)(xb_ + (size_t)i00n * C);                            \
    G01 = *(const f16x8*)(xb_ + (size_t)i01n * C);                            \
    G10 = *(const f16x8*)(xb_ + (size_t)i10n * C);                            \
    G11 = *(const f16x8*)(xb_ + (size_t)i11n * C);                            \
    const f16* wb_ = wbase + kk_ * 256 + cb_;                                 \
    W0 = *(const f16x8*)(wb_);                                                \
    W1 = *(const f16x8*)(wb_ + 16 * KTOT);                                    \
    W2 = *(const f16x8*)(wb_ + 32 * KTOT);                                    \
    W3 = *(const f16x8*)(wb_ + 48 * KTOT);                                    \
    V00 = w00n; V01 = w01n; V10 = w10n; V11 = w11n;                           \
} while (0)

// interp in f32, store f16x8 to St
#define CONSUME(G00, G01, G10, G11, V00, V01, V10, V11, buf_) do {            \
    f16x8 r_;                                                                 \
    _Pragma("unroll")                                                         \
    for (int j_ = 0; j_ < 8; j_++) {                                          \
        float s_ = V00 * (float)G00[j_] + V01 * (float)G01[j_] +              \
                   V10 * (float)G10[j_] + V11 * (float)G11[j_];               \
        r_[j_] = (f16)s_;                                                     \
    }                                                                         \
    *(f16x8*)&St[buf_][px][cg] = r_;                                          \
} while (0)

#define DOMFMA(W0, W1, W2, W3, buf_) do {                                     \
    f16x8 bf0 = *(const f16x8*)&St[buf_][ 0 + ln][kh];                        \
    f16x8 bf1 = *(const f16x8*)&St[buf_][16 + ln][kh];                        \
    f16x8 bf2 = *(const f16x8*)&St[buf_][32 + ln][kh];                        \
    f16x8 bf3 = *(const f16x8*)&St[buf_][48 + ln][kh];                        \
    acc[0][0] = __builtin_amdgcn_mfma_f32_16x16x32_f16(W0, bf0, acc[0][0], 0, 0, 0); \
    acc[0][1] = __builtin_amdgcn_mfma_f32_16x16x32_f16(W0, bf1, acc[0][1], 0, 0, 0); \
    acc[0][2] = __builtin_amdgcn_mfma_f32_16x16x32_f16(W0, bf2, acc[0][2], 0, 0, 0); \
    acc[0][3] = __builtin_amdgcn_mfma_f32_16x16x32_f16(W0, bf3, acc[0][3], 0, 0, 0); \
    acc[1][0] = __builtin_amdgcn_mfma_f32_16x16x32_f16(W1, bf0, acc[1][0], 0, 0, 0); \
    acc[1][1] = __builtin_amdgcn_mfma_f32_16x16x32_f16(W1, bf1, acc[1][1], 0, 0, 0); \
    acc[1][2] = __builtin_amdgcn_mfma_f32_16x16x32_f16(W1, bf2, acc[1][2], 0, 0, 0); \
    acc[1][3] = __builtin_amdgcn_mfma_f32_16x16x32_f16(W1, bf3, acc[1][3], 0, 0, 0); \
    acc[2][0] = __builtin_amdgcn_mfma_f32_16x16x32_f16(W2, bf0, acc[2][0], 0, 0, 0); \
    acc[2][1] = __builtin_amdgcn_mfma_f32_16x16x32_f16(W2, bf1, acc[2][1], 0, 0, 0); \
    acc[2][2] = __builtin_amdgcn_mfma_f32_16x16x32_f16(W2, bf2, acc[2][2], 0, 0, 0); \
    acc[2][3] = __builtin_amdgcn_mfma_f32_16x16x32_f16(W2, bf3, acc[2][3], 0, 0, 0); \
    acc[3][0] = __builtin_amdgcn_mfma_f32_16x16x32_f16(W3, bf0, acc[3][0], 0, 0, 0); \
    acc[3][1] = __builtin_amdgcn_mfma_f32_16x16x32_f16(W3, bf1, acc[3][1], 0, 0, 0); \
    acc[3][2] = __builtin_amdgcn_mfma_f32_16x16x32_f16(W3, bf2, acc[3][2], 0, 0, 0); \
    acc[3][3] = __builtin_amdgcn_mfma_f32_16x16x32_f16(W3, bf3, acc[3][3], 0, 0, 0); \
} while (0)

    f16x8 ga00, ga01, ga10, ga11, gb00, gb01, gb10, gb11;
    f16x8 wa0, wa1, wa2, wa3, wb0, wb1, wb2, wb3;
    float va00, va01, va10, va11, vb00, vb01, vb10, vb11;

    RECOMP(0);
    ISSUE(ga00, ga01, ga10, ga11, wa0, wa1, wa2, wa3,
          va00, va01, va10, va11, 0);

    for (int ch = 0; ch < 72; ch += 2) {
        {
            int chn = ch + 1;
            if ((chn & 7) == 0) RECOMP(chn >> 3);
            ISSUE(gb00, gb01, gb10, gb11, wb0, wb1, wb2, wb3,
                  vb00, vb01, vb10, vb11, chn);
        }
        CONSUME(ga00, ga01, ga10, ga11, va00, va01, va10, va11, 0);
        BAR_FULL();
        DOMFMA(wa0, wa1, wa2, wa3, 0);
        {
            int chn = ch + 2 < 72 ? ch + 2 : 71;
            if ((chn & 7) == 0) RECOMP(chn >> 3);
            ISSUE(ga00, ga01, ga10, ga11, wa0, wa1, wa2, wa3,
                  va00, va01, va10, va11, chn);
        }
        CONSUME(gb00, gb01, gb10, gb11, vb00, vb01, vb10, vb11, 1);
        BAR_FULL();
        DOMFMA(wb0, wb1, wb2, wb3, 1);
    }

    // epilogue: bias + store (D: row=(l>>4)*4+r -> o, col=l&15 -> p)
    #pragma unroll
    for (int mf = 0; mf < 4; mf++) {
        #pragma unroll
        for (int rr = 0; rr < 4; rr++) {
            int o = wo + mf * 16 + (l >> 4) * 4 + rr;
            float bias = cb[o];
            #pragma unroll
            for (int nf = 0; nf < 4; nf++) {
                int p = p0 + nf * 16 + ln;
                out[((size_t)(b * O + o)) * HW + p] = acc[mf][nf][rr] + bias;
            }
        }
    }
#undef RECOMP
#undef ISSUE
#undef CONSUME
#undef DOMFMA
}

extern "C" void kernel_launch(void* const* d_in, const int* in_sizes, int n_in,
                              void* d_out, int out_size, void* d_ws, size_t ws_size,
                              hipStream_t stream) {
    const float* x  = (const float*)d_in[0];
    const float* ow = (const float*)d_in[1];
    const float* ob = (const float*)d_in[2];
    const float* cw = (const float*)d_in[3];
    const float* cb = (const float*)d_in[4];
    float* out = (float*)d_out;

    char* ws = (char*)d_ws;
    float* params = (float*)ws;                         // 4,718,592 B
    f16*   Wt2    = (f16*)(ws + 4718592);               // 1,179,648 B
    f16*   xt16   = (f16*)(ws + 4718592 + 1179648);     // 16,777,216 B
    f16*   Wo2    = (f16*)(ws + 4718592 + 1179648 + 16777216); // 147,456 B

    wprep_kernel<<<(O * KTOT + 32 * KTOT + 255) / 256, 256, 0, stream>>>(cw, ow, Wt2, Wo2);
    transpose_x_kernel<<<dim3(64, 4, NB), 256, 0, stream>>>(x, xt16);
    offset_mfma_kernel<<<256, 256, 0, stream>>>(xt16, Wo2, ob, params);
    deform_mfma_kernel<<<512, 256, 0, stream>>>(xt16, Wt2, params, cb, out);
}